// Round 8
// baseline (465.831 us; speedup 1.0000x reference)
//
#include <hip/hip_runtime.h>
#include <math.h>

#define NVIEW 4
#define BATCH 4
#define NSEQ  256
#define CDIM  768
#define HEADS 12
#define HD    64

typedef __attribute__((ext_vector_type(8))) short   short8;
typedef __attribute__((ext_vector_type(8))) unsigned short ushort8;
typedef __attribute__((ext_vector_type(4))) float   float4v;

typedef const __attribute__((address_space(1))) void gas_t;
typedef       __attribute__((address_space(3))) void las_t;

__device__ __forceinline__ unsigned short f2b(float x)
{
    union { float f; unsigned u; } c; c.f = x;
    unsigned r = (c.u + 0x7FFFu + ((c.u >> 16) & 1u)) >> 16;
    return (unsigned short)r;
}

// ---------------------------------------------------------------------------
// f32 -> bf16 conversion (n must be multiple of 8)
// ---------------------------------------------------------------------------
__global__ void conv_bf16(const float* __restrict__ src, unsigned short* __restrict__ dst, int n)
{
    int idx = (blockIdx.x * 256 + threadIdx.x) * 8;
    if (idx >= n) return;
    float4 a = *(const float4*)(src + idx);
    float4 b = *(const float4*)(src + idx + 4);
    ushort8 o;
    o[0] = f2b(a.x); o[1] = f2b(a.y); o[2] = f2b(a.z); o[3] = f2b(a.w);
    o[4] = f2b(b.x); o[5] = f2b(b.y); o[6] = f2b(b.z); o[7] = f2b(b.w);
    *(ushort8*)(dst + idx) = o;
}

// ---------------------------------------------------------------------------
// LayerNorm -> bf16 out
// ---------------------------------------------------------------------------
__device__ __forceinline__ void block_ln_row_b(const float* __restrict__ xrow,
                                               const float* __restrict__ g,
                                               const float* __restrict__ b,
                                               unsigned short* __restrict__ orow)
{
    const int t = threadIdx.x;
    float x0 = xrow[t], x1 = xrow[t + 256], x2 = xrow[t + 512];
    float s  = x0 + x1 + x2;
    float s2 = x0 * x0 + x1 * x1 + x2 * x2;
    #pragma unroll
    for (int off = 32; off > 0; off >>= 1) {
        s  += __shfl_down(s, off);
        s2 += __shfl_down(s2, off);
    }
    __shared__ float w1[4], w2[4];
    if ((t & 63) == 0) { w1[t >> 6] = s; w2[t >> 6] = s2; }
    __syncthreads();
    float S  = w1[0] + w1[1] + w1[2] + w1[3];
    float S2 = w2[0] + w2[1] + w2[2] + w2[3];
    float mean = S * (1.0f / 768.0f);
    float var  = S2 * (1.0f / 768.0f) - mean * mean;
    float inv  = rsqrtf(var + 1e-6f);
    orow[t]       = f2b((x0 - mean) * inv * g[t]       + b[t]);
    orow[t + 256] = f2b((x1 - mean) * inv * g[t + 256] + b[t + 256]);
    orow[t + 512] = f2b((x2 - mean) * inv * g[t + 512] + b[t + 512]);
}

// X:[B,V,N,C] -> Xn bf16 [V,B,N,C]
__global__ void ln1_kernel(const float* __restrict__ X, const float* __restrict__ g,
                           const float* __restrict__ b, unsigned short* __restrict__ Xn)
{
    int rid = blockIdx.x;
    int n  = rid & 255;
    int bv = rid >> 8;
    int bb = bv >> 2, v = bv & 3;
    const float* xrow = X + (long)rid * CDIM;
    unsigned short* orow = Xn + ((long)(v * 4 + bb) * 256 + n) * CDIM;
    block_ln_row_b(xrow, g, b, orow);
}

// f32 in [V,B,N,C] -> bf16 out, per-view gamma/beta
__global__ void ln2_kernel(const float* __restrict__ Xin, const float* __restrict__ g,
                           const float* __restrict__ b, unsigned short* __restrict__ Out)
{
    int rid = blockIdx.x;
    int v = rid >> 10;
    const float* xrow = Xin + (long)rid * CDIM;
    block_ln_row_b(xrow, g + v * CDIM, b + v * CDIM, Out + (long)rid * CDIM);
}

// ---------------------------------------------------------------------------
// bf16 MFMA grouped GEMM: out[v] = A[v](M,K) * W[v]^T(N,K) + epilogue
// TM x 128 tile, BK=64. TM=128: waves 2x2, 4x4 acc; TM=64: waves 1x4, 4x2 acc.
// Row = 8 chunks of 16B; chunk c stored at physical slot p = c ^ (row&7).
// EPI: 0=store bf16  1=+bias f32  2=+bias,gelu bf16  3=+bias,+resid(f32) bf16
//      4=(+bias)*2 f32  7=QKV special: cols<1536 bf16 to out, V-cols transposed to vt
// ---------------------------------------------------------------------------
template <int EPI, int TM, typename OT>
__launch_bounds__(256, 2)
__global__ void gemm_bf16(const unsigned short* __restrict__ A,
                          const unsigned short* __restrict__ W,
                          const float* __restrict__ bias, const float* __restrict__ resid,
                          OT* __restrict__ out, unsigned short* __restrict__ vt,
                          int M, int N, int K,
                          long wStride, long wOff, int bStride, int bOff)
{
    const int v = blockIdx.z;
    const unsigned short* Av = A + (long)v * M * K;
    const unsigned short* Wv = W + v * wStride + wOff;

    __shared__ unsigned short As[TM * 64];
    __shared__ unsigned short Bs[128 * 64];

    const int tid  = threadIdx.x;
    const int lane = tid & 63;
    const int wave = tid >> 6;
    const int l15  = lane & 15;
    const int quad = lane >> 4;
    const int row0 = blockIdx.y * TM, col0 = blockIdx.x * 128;

    constexpr int MI = 4;
    constexpr int NI = (TM == 128) ? 4 : 2;
    const int mw = (TM == 128) ? (wave & 1) * 64 : 0;
    const int nw = (TM == 128) ? (wave >> 1) * 64 : wave * 32;

    float4v acc[MI][NI];
    #pragma unroll
    for (int i = 0; i < MI; ++i)
        #pragma unroll
        for (int j = 0; j < NI; ++j)
            acc[i][j] = (float4v){0.f, 0.f, 0.f, 0.f};

    const int lr8 = lane >> 3;   // 0..7 row-within-group
    const int p8  = lane & 7;    // physical 16B slot

    for (int k0 = 0; k0 < K; k0 += 64) {
        __syncthreads();
        #pragma unroll
        for (int g = 0; g < TM / 32; ++g) {
            int G = wave * (TM / 32) + g;
            int r = G * 8 + lr8;
            int c = p8 ^ (r & 7);
            const unsigned short* sa = Av + (long)(row0 + r) * K + k0 + c * 8;
            __builtin_amdgcn_global_load_lds((gas_t*)sa, (las_t*)&As[G * 512], 16, 0, 0);
        }
        #pragma unroll
        for (int g = 0; g < 4; ++g) {
            int G = wave * 4 + g;
            int r = G * 8 + lr8;
            int c = p8 ^ (r & 7);
            const unsigned short* sw = Wv + (long)(col0 + r) * K + k0 + c * 8;
            __builtin_amdgcn_global_load_lds((gas_t*)sw, (las_t*)&Bs[G * 512], 16, 0, 0);
        }
        __syncthreads();

        #pragma unroll
        for (int ks = 0; ks < 2; ++ks) {
            short8 af[MI], bfr[NI];
            #pragma unroll
            for (int mi = 0; mi < MI; ++mi) {
                int m = mw + mi * 16 + l15;
                int p = (ks * 4 + quad) ^ (m & 7);
                af[mi] = *(const short8*)&As[m * 64 + p * 8];
            }
            #pragma unroll
            for (int ni = 0; ni < NI; ++ni) {
                int n = nw + ni * 16 + l15;
                int p = (ks * 4 + quad) ^ (n & 7);
                bfr[ni] = *(const short8*)&Bs[n * 64 + p * 8];
            }
            #pragma unroll
            for (int mi = 0; mi < MI; ++mi)
                #pragma unroll
                for (int ni = 0; ni < NI; ++ni)
                    acc[mi][ni] = __builtin_amdgcn_mfma_f32_16x16x32_bf16(af[mi], bfr[ni], acc[mi][ni], 0, 0, 0);
        }
    }

    #pragma unroll
    for (int mi = 0; mi < MI; ++mi) {
        #pragma unroll
        for (int ni = 0; ni < NI; ++ni) {
            int rowb = row0 + mw + mi * 16 + quad * 4;
            int col  = col0 + nw + ni * 16 + l15;
            float bval = 0.f;
            if (EPI >= 1 && EPI <= 4) bval = bias[v * bStride + bOff + col];
            #pragma unroll
            for (int r = 0; r < 4; ++r) {
                float x = acc[mi][ni][r] + bval;
                long off = (long)v * M * N + (long)(rowb + r) * N + col;
                if constexpr (EPI == 2) {
                    x = 0.5f * x * (1.0f + erff(x * 0.70710678118654752f));
                } else if constexpr (EPI == 3) {
                    x += resid[off];
                } else if constexpr (EPI == 4) {
                    x *= 2.0f;
                }
                if constexpr (EPI == 7) {
                    if (col0 < 1536) {
                        ((unsigned short*)out)[off] = f2b(x);
                    } else {
                        int cc  = col - 1536;
                        int hh  = cc >> 6, ee = cc & 63;
                        int row = rowb + r;
                        int bb2 = row >> 8, nn2 = row & 255;
                        vt[((long)((v * 4 + bb2) * 12 + hh)) * 16384 + ee * 256 + nn2] = f2b(x);
                    }
                } else if constexpr (sizeof(OT) == 2) {
                    ((unsigned short*)out)[off] = f2b(x);
                } else {
                    ((float*)out)[off] = x;
                }
            }
        }
    }
}

// ---------------------------------------------------------------------------
// Fused MFMA fusion-attention v2 (S^T trick, producer-transposed V).
// grid (qt=4, b*h=48, i=4); block 256 = 4 waves; each wave owns 16 query rows.
// S^T = K·Q^T so lane holds fixed q=l15; P written packed; V B-frags direct
// from global VT[(j*4+b)*12+h][d][n] (L2-hot, 16x reuse).
// ---------------------------------------------------------------------------
__launch_bounds__(256, 3)
__global__ void fusion_attn_mfma(const unsigned short* __restrict__ QKV,
                                 const unsigned short* __restrict__ VT,
                                 unsigned short* __restrict__ ctx)
{
    const int qt = blockIdx.x;
    const int b  = blockIdx.y / HEADS;
    const int h  = blockIdx.y % HEADS;
    const int i  = blockIdx.z;
    const int tid  = threadIdx.x;
    const int lane = tid & 63;
    const int wave = tid >> 6;
    const int l15  = lane & 15;
    const int quad = lane >> 4;

    __shared__ unsigned short Qs[64 * 72];     //  9216 B
    __shared__ unsigned short Ks[128 * 64];    // 16384 B
    __shared__ unsigned short Ps[64 * 136];    // 17408 B (wave-private rows)

    {   // stage Q tile
        int r = tid >> 2, p16 = (tid & 3) * 16;
        const unsigned short* src = QKV + ((long)((i * 4 + b) * 256 + qt * 64 + r)) * 2304 + h * 64 + p16;
        *(ushort8*)(&Qs[r * 72 + p16])     = *(const ushort8*)(src);
        *(ushort8*)(&Qs[r * 72 + p16 + 8]) = *(const ushort8*)(src + 8);
    }

    float4v acc_o[4];
    #pragma unroll
    for (int e = 0; e < 4; ++e) acc_o[e] = (float4v){0.f, 0.f, 0.f, 0.f};

    for (int j = 0; j < 4; ++j) {
        const unsigned short* Kb  = QKV + ((long)((j * 4 + b) * 256)) * 2304 + 768 + h * 64;
        const unsigned short* VTb = VT + ((long)((j * 4 + b) * 12 + h)) * 16384;

        float4v sacc[16];
        #pragma unroll
        for (int t = 0; t < 16; ++t) sacc[t] = (float4v){0.f, 0.f, 0.f, 0.f};

        // ---- S^T = K Q^T over 2 half-tiles of 128 keys ----
        for (int half = 0; half < 2; ++half) {
            __syncthreads();
            #pragma unroll
            for (int g = 0; g < 4; ++g) {
                int R = wave * 32 + g * 8;
                int r = R + (lane >> 3);
                int p = lane & 7;
                int c = (p - (r & 7)) & 7;
                const unsigned short* src = Kb + (long)(half * 128 + r) * 2304 + c * 8;
                __builtin_amdgcn_global_load_lds((gas_t*)src, (las_t*)&Ks[R * 64], 16, 0, 0);
            }
            __syncthreads();
            #pragma unroll
            for (int ks = 0; ks < 2; ++ks) {
                int lcq = ks * 4 + quad;
                short8 qf = *(const short8*)&Qs[(wave * 16 + l15) * 72 + lcq * 8];
                #pragma unroll
                for (int nn = 0; nn < 8; ++nn) {
                    int n = nn * 16 + l15;
                    int p = (lcq + (n & 7)) & 7;
                    short8 kf = *(const short8*)&Ks[n * 64 + p * 8];
                    // A=K (rows n), B=Q (rows q) -> D=S^T: col=q(l15), row=n(quad*4+r)
                    sacc[half * 8 + nn] =
                        __builtin_amdgcn_mfma_f32_16x16x32_bf16(kf, qf, sacc[half * 8 + nn], 0, 0, 0);
                }
            }
        }

        // ---- softmax per q (=l15); n spread over regs + quads ----
        float rmax = -1e30f;
        #pragma unroll
        for (int t = 0; t < 16; ++t)
            #pragma unroll
            for (int r = 0; r < 4; ++r)
                rmax = fmaxf(rmax, sacc[t][r] * 0.125f);
        rmax = fmaxf(rmax, __shfl_xor(rmax, 16));
        rmax = fmaxf(rmax, __shfl_xor(rmax, 32));
        float rsum = 0.f;
        #pragma unroll
        for (int t = 0; t < 16; ++t)
            #pragma unroll
            for (int r = 0; r < 4; ++r) {
                float e = __expf(sacc[t][r] * 0.125f - rmax);
                sacc[t][r] = e;
                rsum += e;
            }
        rsum += __shfl_xor(rsum, 16);
        rsum += __shfl_xor(rsum, 32);
        float invl = 1.0f / rsum;
        // redistribute: lane needs invl for q = quad*4+r
        float invq[4];
        #pragma unroll
        for (int r = 0; r < 4; ++r) invq[r] = __shfl(invl, quad * 4 + r);

        // ---- PV over 2 half-tiles; Ps is wave-private ----
        float4v pv[4];
        #pragma unroll
        for (int e = 0; e < 4; ++e) pv[e] = (float4v){0.f, 0.f, 0.f, 0.f};

        for (int half = 0; half < 2; ++half) {
            // packed P write: 4 consecutive n per lane -> one b64
            #pragma unroll
            for (int nn = 0; nn < 8; ++nn) {
                uint2 pk;
                pk.x = (unsigned)f2b(sacc[half * 8 + nn][0]) | ((unsigned)f2b(sacc[half * 8 + nn][1]) << 16);
                pk.y = (unsigned)f2b(sacc[half * 8 + nn][2]) | ((unsigned)f2b(sacc[half * 8 + nn][3]) << 16);
                *(uint2*)&Ps[(wave * 16 + l15) * 136 + nn * 16 + quad * 4] = pk;
            }
            __syncthreads();   // order Ps writes before cross-lane reads (wave-private but cross-lane)
            #pragma unroll
            for (int ks = 0; ks < 4; ++ks) {
                short8 pf = *(const short8*)&Ps[(wave * 16 + l15) * 136 + ks * 32 + quad * 8];
                #pragma unroll
                for (int et = 0; et < 4; ++et) {
                    short8 vf = *(const short8*)(VTb + (long)(et * 16 + l15) * 256 + half * 128 + ks * 32 + quad * 8);
                    pv[et] = __builtin_amdgcn_mfma_f32_16x16x32_bf16(pf, vf, pv[et], 0, 0, 0);
                }
            }
            __syncthreads();   // Ps reads done before next half's writes
        }
        #pragma unroll
        for (int et = 0; et < 4; ++et)
            #pragma unroll
            for (int r = 0; r < 4; ++r)
                acc_o[et][r] += pv[et][r] * invq[r];
    }

    #pragma unroll
    for (int et = 0; et < 4; ++et)
        #pragma unroll
        for (int r = 0; r < 4; ++r) {
            int row = (i * 4 + b) * 256 + qt * 64 + wave * 16 + quad * 4 + r;
            int col = h * 64 + et * 16 + l15;
            ctx[(long)row * 768 + col] = f2b(acc_o[et][r] * 0.25f);
        }
}

// ---------------------------------------------------------------------------
// qh: one wave per output row d (768 blocks x 4 waves).
// ---------------------------------------------------------------------------
__launch_bounds__(256, 4)
__global__ void qh_kernel(const float* __restrict__ query, const float* __restrict__ Win,
                          const float* __restrict__ Bin, float* __restrict__ QH)
{
    const int bi   = blockIdx.x;
    const int v    = bi / 192;
    const int dblk = bi - v * 192;
    const int t    = threadIdx.x;
    const int wave = t >> 6;
    const int lane = t & 63;
    const int d    = dblk * 4 + wave;

    __shared__ float qs[768];
    for (int idx = t; idx < 768; idx += 256) qs[idx] = query[idx];
    __syncthreads();

    const float* w = Win + ((long)v * 2304 + d) * 768;
    float acc = 0.f;
    #pragma unroll
    for (int k = 0; k < 3; ++k) {
        int c = k * 256 + lane * 4;
        float4 w4 = *(const float4*)(w + c);
        float4 q4 = *(const float4*)&qs[c];
        acc += w4.x * q4.x + w4.y * q4.y + w4.z * q4.z + w4.w * q4.w;
    }
    #pragma unroll
    for (int off = 32; off > 0; off >>= 1) acc += __shfl_down(acc, off);
    if (lane == 0)
        QH[v * 768 + d] = acc + Bin[(long)v * 2304 + d];
}

// ---------------------------------------------------------------------------
// Learnable-query cross attention (f32). KVH [V,B,N,1536]: k then v.
// ---------------------------------------------------------------------------
__launch_bounds__(256, 2)
__global__ void cross_attn(const float* __restrict__ KVH, const float* __restrict__ QH,
                           float* __restrict__ C2)
{
    const int h = blockIdx.x, b = blockIdx.y, v = blockIdx.z;
    const int t = threadIdx.x;
    __shared__ float qv[64];
    __shared__ float p[256];
    __shared__ float part[4][64];
    __shared__ float wred[4], wred2[4];

    if (t < 64) qv[t] = QH[(v * 12 + h) * 64 + t];
    __syncthreads();

    const float* krow = KVH + ((long)((v * 4 + b) * 256 + t)) * 1536 + h * 64;
    float s = 0.f;
    #pragma unroll
    for (int e = 0; e < 64; e += 4) {
        float4 k4 = *(const float4*)(krow + e);
        s += qv[e] * k4.x + qv[e + 1] * k4.y + qv[e + 2] * k4.z + qv[e + 3] * k4.w;
    }
    s *= 0.125f;
    float m4 = s;
    #pragma unroll
    for (int off = 32; off > 0; off >>= 1) m4 = fmaxf(m4, __shfl_down(m4, off));
    if ((t & 63) == 0) wred[t >> 6] = m4;
    __syncthreads();
    float rmax = fmaxf(fmaxf(wred[0], wred[1]), fmaxf(wred[2], wred[3]));
    float ev = __expf(s - rmax);
    p[t] = ev;
    float s4 = ev;
    #pragma unroll
    for (int off = 32; off > 0; off >>= 1) s4 += __shfl_down(s4, off);
    if ((t & 63) == 0) wred2[t >> 6] = s4;
    __syncthreads();
    float inv = 1.0f / (wred2[0] + wred2[1] + wred2[2] + wred2[3]);

    const int e = t & 63, ch = t >> 6;
    const float* vbase = KVH + ((long)((v * 4 + b) * 256)) * 1536 + 768 + h * 64 + e;
    float accv = 0.f;
    for (int m = ch * 64; m < ch * 64 + 64; ++m)
        accv += p[m] * vbase[(long)m * 1536];
    part[ch][e] = accv;
    __syncthreads();
    if (t < 64)
        C2[(v * 4 + b) * 768 + h * 64 + t] =
            (part[0][t] + part[1][t] + part[2][t] + part[3][t]) * inv;
}

// ---------------------------------------------------------------------------
// out stage 1: one wave per output row d; 768 blocks x 4 waves.
// ---------------------------------------------------------------------------
__launch_bounds__(256, 4)
__global__ void out_matvec(const float* __restrict__ C2, const float* __restrict__ Wout,
                           const float* __restrict__ Bout, float* __restrict__ obc)
{
    const int bi   = blockIdx.x;
    const int v    = bi / 192;
    const int dblk = bi - v * 192;
    const int t    = threadIdx.x;
    const int wave = t >> 6;
    const int lane = t & 63;
    const int d    = dblk * 4 + wave;

    __shared__ float c2s[3072];
    #pragma unroll
    for (int idx = 0; idx < 3072; idx += 256) c2s[idx + t] = C2[v * 3072 + idx + t];
    __syncthreads();

    const float* w = Wout + ((long)v * 768 + d) * 768;
    float acc0 = 0.f, acc1 = 0.f, acc2 = 0.f, acc3 = 0.f;
    #pragma unroll
    for (int k = 0; k < 3; ++k) {
        int c = k * 256 + lane * 4;
        float4 w4 = *(const float4*)(w + c);
        float4 a0 = *(const float4*)&c2s[c];
        float4 a1 = *(const float4*)&c2s[768 + c];
        float4 a2 = *(const float4*)&c2s[1536 + c];
        float4 a3 = *(const float4*)&c2s[2304 + c];
        acc0 += w4.x * a0.x + w4.y * a0.y + w4.z * a0.z + w4.w * a0.w;
        acc1 += w4.x * a1.x + w4.y * a1.y + w4.z * a1.z + w4.w * a1.w;
        acc2 += w4.x * a2.x + w4.y * a2.y + w4.z * a2.z + w4.w * a2.w;
        acc3 += w4.x * a3.x + w4.y * a3.y + w4.z * a3.z + w4.w * a3.w;
    }
    #pragma unroll
    for (int off = 32; off > 0; off >>= 1) {
        acc0 += __shfl_down(acc0, off);
        acc1 += __shfl_down(acc1, off);
        acc2 += __shfl_down(acc2, off);
        acc3 += __shfl_down(acc3, off);
    }
    if (lane == 0) {
        float bb = Bout[v * 768 + d];
        obc[0 * 3072 + v * 768 + d] = acc0 + bb;
        obc[1 * 3072 + v * 768 + d] = acc1 + bb;
        obc[2 * 3072 + v * 768 + d] = acc2 + bb;
        obc[3 * 3072 + v * 768 + d] = acc3 + bb;
    }
}

// ---------------------------------------------------------------------------
// out stage 2: broadcast over N
// ---------------------------------------------------------------------------
__launch_bounds__(256, 4)
__global__ void out_bcast(const float* __restrict__ obc, float* __restrict__ out)
{
    const int b  = blockIdx.x >> 6;
    const int n0 = (blockIdx.x & 63) * 4;
    const int t  = threadIdx.x;
    const float4* src = (const float4*)(obc + (long)b * 3072);
    float4 v0 = src[t], v1 = src[t + 256], v2 = src[t + 512];
    float4* dst = (float4*)(out + ((long)(b * 256 + n0)) * 3072);
    #pragma unroll
    for (int r = 0; r < 4; ++r) {
        dst[r * 768 + t]       = v0;
        dst[r * 768 + t + 256] = v1;
        dst[r * 768 + t + 512] = v2;
    }
}

// ---------------------------------------------------------------------------
extern "C" void kernel_launch(void* const* d_in, const int* in_sizes, int n_in,
                              void* d_out, int out_size, void* d_ws, size_t ws_size,
                              hipStream_t stream)
{
    const float* X        = (const float*)d_in[0];
    const float* n1g      = (const float*)d_in[1];
    const float* n1b      = (const float*)d_in[2];
    const float* qkv_w    = (const float*)d_in[3];
    const float* proj_w   = (const float*)d_in[4];
    const float* proj_b   = (const float*)d_in[5];
    const float* n2g      = (const float*)d_in[6];
    const float* n2b      = (const float*)d_in[7];
    const float* fc1_w    = (const float*)d_in[8];
    const float* fc1_b    = (const float*)d_in[9];
    const float* fc2_w    = (const float*)d_in[10];
    const float* fc2_b    = (const float*)d_in[11];
    const float* query    = (const float*)d_in[12];
    const float* mha_in_w = (const float*)d_in[13];
    const float* mha_in_b = (const float*)d_in[14];
    const float* mha_out_w= (const float*)d_in[15];
    const float* mha_out_b= (const float*)d_in[16];
    float* out = (float*)d_out;

    char* wsb = (char*)d_ws;
    unsigned short* wbuf = (unsigned short*)wsb;                    // 18,874,368 B
    unsigned short* rgA  = (unsigned short*)(wsb + 18874368);       //  6,291,456 B (Xn -> ctx -> h -> x2)
    char*           rgB  = wsb + 25165824;                          // 25,165,824 B (QKV+VT -> h1 -> KVH)
    float*          xbuf = (float*)(wsb + 50331648);                // 12,582,912 B (x residual, f32)
    float*          qh   = (float*)(wsb + 62914560);
    float*          c2   = (float*)(wsb + 62926848);
    float*          obc  = (float*)(wsb + 62976000);                // 49,152 B

    unsigned short* QKV = (unsigned short*)rgB;                     // 18,874,368 B (Q/K rows; V cols unused)
    unsigned short* VTb = (unsigned short*)(wsb + 44040192);        //  6,291,456 B (V transposed; dead before H1)
    unsigned short* H1  = (unsigned short*)rgB;
    float*          KVH = (float*)rgB;

    // 1. qkv weights -> bf16, LN1 -> Xn bf16
    conv_bf16<<<3456, 256, 0, stream>>>(qkv_w, wbuf, 7077888);
    ln1_kernel<<<4096, 256, 0, stream>>>(X, n1g, n1b, rgA);
    // 2. QKV = Xn @ qkv_w^T; Q/K rows to QKV, V transposed to VTb  (EPI=7)
    gemm_bf16<7, 128, unsigned short><<<dim3(18, 8, 4), 256, 0, stream>>>(
        rgA, wbuf, nullptr, nullptr, QKV, VTb, 1024, 2304, 768, 2304L * 768, 0, 0, 0);
    // 3. fusion attention -> ctx_mean bf16 [V,1024,768]
    fusion_attn_mfma<<<dim3(4, 48, 4), 256, 0, stream>>>(QKV, VTb, rgA);
    // 4. x = 2*(ctx @ proj_w^T + proj_b)  f32    (TM=64)
    conv_bf16<<<1152, 256, 0, stream>>>(proj_w, wbuf, 2359296);
    gemm_bf16<4, 64, float><<<dim3(6, 16, 4), 256, 0, stream>>>(
        rgA, wbuf, proj_b, nullptr, xbuf, nullptr, 1024, 768, 768, 768L * 768, 0, 768, 0);
    // 5. h = LN2(x) bf16
    ln2_kernel<<<4096, 256, 0, stream>>>(xbuf, n2g, n2b, rgA);
    // 6. h1 = gelu(h @ fc1_w^T + fc1_b) bf16  (TM=128)
    conv_bf16<<<4608, 256, 0, stream>>>(fc1_w, wbuf, 9437184);
    gemm_bf16<2, 128, unsigned short><<<dim3(24, 8, 4), 256, 0, stream>>>(
        rgA, wbuf, fc1_b, nullptr, H1, nullptr, 1024, 3072, 768, 3072L * 768, 0, 3072, 0);
    // 7. x2 = x + (h1 @ fc2_w^T + fc2_b) bf16   (TM=64)
    conv_bf16<<<4608, 256, 0, stream>>>(fc2_w, wbuf, 9437184);
    gemm_bf16<3, 64, unsigned short><<<dim3(6, 16, 4), 256, 0, stream>>>(
        H1, wbuf, fc2_b, xbuf, rgA, nullptr, 1024, 768, 3072, 768L * 3072, 0, 768, 0);
    // 8. KVH = x2 @ [wk;wv]^T + [bk;bv]  f32   (TM=64)
    conv_bf16<<<3456, 256, 0, stream>>>(mha_in_w, wbuf, 7077888);
    gemm_bf16<1, 64, float><<<dim3(12, 16, 4), 256, 0, stream>>>(
        rgA, wbuf, mha_in_b, nullptr, KVH, nullptr, 1024, 1536, 768, 2304L * 768, 768L * 768, 2304, 768);
    // 9. small tail
    qh_kernel<<<768, 256, 0, stream>>>(query, mha_in_w, mha_in_b, qh);
    cross_attn<<<dim3(12, 4, 4), 256, 0, stream>>>(KVH, qh, c2);
    out_matvec<<<768, 256, 0, stream>>>(c2, mha_out_w, mha_out_b, obc);
    out_bcast<<<256, 256, 0, stream>>>(obc, out);
}